// Round 11
// baseline (472.951 us; speedup 1.0000x reference)
//
#include <hip/hip_runtime.h>
#include <hip/hip_bf16.h>

typedef __bf16 bf16x8 __attribute__((ext_vector_type(8)));
typedef float  f32x4  __attribute__((ext_vector_type(4)));

static constexpr int S  = 64;    // DIM_S
static constexpr int C  = 8;     // DIM_C (experts)
static constexpr int HD = 256;   // hidden width

__device__ __forceinline__ unsigned short f2bf(float f) {
  __hip_bfloat16 b = __float2bfloat16(f);
  unsigned short u;
  __builtin_memcpy(&u, &b, 2);
  return u;
}

// async global->LDS DMA, 16 B per lane; lds dest = wave-uniform base + lane*16
__device__ __forceinline__ void gl2lds16(const void* g, void* l) {
  __builtin_amdgcn_global_load_lds(
      (const __attribute__((address_space(1))) unsigned int*)g,
      (__attribute__((address_space(3))) unsigned int*)l, 16, 0, 0);
}

// LDS-tiled transposes, coalesced both sides.  (unchanged, verified)
// blocks 0..511:  W2 [C][256k][256n] -> W2T bf16 [C][256n][256k]
// blocks 512..639: W1 [C][64s][256h] -> W1T bf16 [C][256h][64s]
__global__ __launch_bounds__(256) void prep_weights(
    const float* __restrict__ W1, const float* __restrict__ W2,
    unsigned short* __restrict__ W1T, unsigned short* __restrict__ W2T)
{
  __shared__ float tile[32][33];
  const int tid = threadIdx.x, cl = tid & 31, r0 = tid >> 5;
  const int b = blockIdx.x;
  if (b < 512) {
    const int c = b >> 6, t = b & 63, kt = t >> 3, nt = t & 7;
    const float* src = W2 + c * 65536;
    #pragma unroll
    for (int i = 0; i < 4; ++i) {
      int r = r0 + 8 * i;
      tile[r][cl] = src[(kt * 32 + r) * 256 + nt * 32 + cl];
    }
    __syncthreads();
    unsigned short* dst = W2T + c * 65536;
    #pragma unroll
    for (int i = 0; i < 4; ++i) {
      int r = r0 + 8 * i;
      dst[(nt * 32 + r) * 256 + kt * 32 + cl] = f2bf(tile[cl][r]);
    }
  } else {
    const int bb = b - 512;
    const int c = bb >> 4, t = bb & 15, st2 = t >> 3, ht = t & 7;
    const float* src = W1 + c * 16384;
    #pragma unroll
    for (int i = 0; i < 4; ++i) {
      int r = r0 + 8 * i;
      tile[r][cl] = src[(st2 * 32 + r) * 256 + ht * 32 + cl];
    }
    __syncthreads();
    unsigned short* dst = W1T + c * 16384;
    #pragma unroll
    for (int i = 0; i < 4; ++i) {
      int r = r0 + 8 * i;
      dst[(ht * 32 + r) * 64 + st2 * 32 + cl] = f2bf(tile[cl][r]);
    }
  }
}

// One block: 256 batch rows x 1 expert. 4 waves, 64 rows/wave. 16x16x32 MFMA.
// = R10's verified pipeline with ONE structural change: sT (36864 B transpose
// buf, phase-1 only) and sU (32768 B W2 ping-pong, phase-2 only) are
// TIME-DISJOINT (st comes straight from global since R10), so they share one
// 36864 B union buffer.  LDS 69632 -> 36864 B: 4 blocks/CU instead of 2
// (16 waves/CU, 4/SIMD at VGPR<=128).  The W2 prologue DMA sits between two
// barriers (as in R6), but 4 staggered blocks/CU now hide that drain.
// Per-wave work, MFMA structure, chunk cadence: identical to R6/R10.
__global__ __launch_bounds__(256, 4) void moe_fused(
    const float* __restrict__ st,
    const unsigned short* __restrict__ W1T,
    const unsigned short* __restrict__ W2T,
    const float* __restrict__ b1,
    const float* __restrict__ b2,
    const float* __restrict__ W3,
    const float* __restrict__ b3,
    float* __restrict__ out)
{
  constexpr int LDT = 72;   // sT pitch: 64 + 8 pad bf16 (144 B rows, 16B-aligned)

  // union: phase 1 = sT transpose buf [256][LDT] (36864 B);
  //        phase 2 = W2 ping-pong 2 x (32 rows x 256 bf16) (32768 B).
  __shared__ __align__(16) unsigned short sBuf[256 * LDT];
  unsigned short* const sT = sBuf;
  unsigned short* const sU = sBuf;

  const int tid  = threadIdx.x;
  const int lane = tid & 63;
  const int wv   = tid >> 6;          // wave -> batch rows [wv*64, wv*64+64)
  const int l15  = lane & 15;
  const int q    = lane >> 4;
  const int c    = blockIdx.x >> 8;
  const int row0 = (blockIdx.x & 255) * 256;
  const int wrow = row0 + wv * 64;

  const unsigned short* W1c = W1T + c * HD * S;
  const unsigned short* W2c = W2T + c * HD * HD;

  // ---- raw st loads (fp32), then convert in-register to B-frags ----
  // frag (ks,nt): row = wrow + nt*16 + l15, cols ks*32 + q*8 .. +7
  float4 sraw[8][2];   // transient, consumed right below
  #pragma unroll
  for (int nt = 0; nt < 4; ++nt)
    #pragma unroll
    for (int ks = 0; ks < 2; ++ks) {
      const float* rp = st + (size_t)(wrow + nt * 16 + l15) * S + ks * 32 + q * 8;
      sraw[ks * 4 + nt][0] = *reinterpret_cast<const float4*>(rp);
      sraw[ks * 4 + nt][1] = *reinterpret_cast<const float4*>(rp + 4);
    }

  bf16x8 bB[2][4];   // [ks][nt], 32 VGPRs, live through phase 1
  #pragma unroll
  for (int nt = 0; nt < 4; ++nt)
    #pragma unroll
    for (int ks = 0; ks < 2; ++ks) {
      float4 x = sraw[ks * 4 + nt][0], y = sraw[ks * 4 + nt][1];
      union { bf16x8 v; unsigned u[4]; } pk;
      __asm__("v_cvt_pk_bf16_f32 %0, %1, %2" : "=v"(pk.u[0]) : "v"(x.x), "v"(x.y));
      __asm__("v_cvt_pk_bf16_f32 %0, %1, %2" : "=v"(pk.u[1]) : "v"(x.z), "v"(x.w));
      __asm__("v_cvt_pk_bf16_f32 %0, %1, %2" : "=v"(pk.u[2]) : "v"(y.x), "v"(y.y));
      __asm__("v_cvt_pk_bf16_f32 %0, %1, %2" : "=v"(pk.u[3]) : "v"(y.z), "v"(y.w));
      bB[ks][nt] = pk.v;
    }

  // ---- phase 1: h1^T[hidden][batch] = W1^T @ st^T, 4 quarters of 64 hidden ----
  bf16x8 aF[4][4][2];  // [cc][rt][k2]: phase-2 A-frags (m=batch l15, k=hidden)
  #pragma unroll
  for (int cc = 0; cc < 4; ++cc) {
    f32x4 bias[4];
    #pragma unroll
    for (int mt = 0; mt < 4; ++mt)
      bias[mt] = *reinterpret_cast<const f32x4*>(
          b1 + c * HD + cc * 64 + mt * 16 + q * 4);

    // b1 folded into MFMA C-in (verified R6): D row = hidden = q*4+j
    f32x4 acc[4][4];   // [mt(hidden)][nt(batch)]
    #pragma unroll
    for (int mt = 0; mt < 4; ++mt)
      #pragma unroll
      for (int nt = 0; nt < 4; ++nt)
        acc[mt][nt] = bias[mt];

    #pragma unroll
    for (int ks = 0; ks < 2; ++ks) {
      // A-frags: W1T rows (hidden as M), global, L1/L2-hot under c-major grid
      bf16x8 aW[4];
      #pragma unroll
      for (int mt = 0; mt < 4; ++mt)
        aW[mt] = *reinterpret_cast<const bf16x8*>(
            W1c + (cc * 64 + mt * 16 + l15) * S + ks * 32 + q * 8);
      __builtin_amdgcn_s_setprio(1);
      #pragma unroll
      for (int mt = 0; mt < 4; ++mt)
        #pragma unroll
        for (int nt = 0; nt < 4; ++nt)
          acc[mt][nt] = __builtin_amdgcn_mfma_f32_16x16x32_bf16(
              aW[mt], bB[ks][nt], acc[mt][nt], 0, 0, 0);
      __builtin_amdgcn_s_setprio(0);
    }

    // epilogue: relu (bias already in C-in), cvt_pk -> one b64 write.
    // sT rows [wv*64, wv*64+64) are wave-private: lgkmcnt drain, no barrier.
    #pragma unroll
    for (int mt = 0; mt < 4; ++mt) {
      #pragma unroll
      for (int nt = 0; nt < 4; ++nt) {
        float v0 = acc[mt][nt][0]; v0 = v0 > 0.f ? v0 : 0.f;
        float v1 = acc[mt][nt][1]; v1 = v1 > 0.f ? v1 : 0.f;
        float v2 = acc[mt][nt][2]; v2 = v2 > 0.f ? v2 : 0.f;
        float v3 = acc[mt][nt][3]; v3 = v3 > 0.f ? v3 : 0.f;
        uint2 pk;
        __asm__("v_cvt_pk_bf16_f32 %0, %1, %2" : "=v"(pk.x) : "v"(v0), "v"(v1));
        __asm__("v_cvt_pk_bf16_f32 %0, %1, %2" : "=v"(pk.y) : "v"(v2), "v"(v3));
        *reinterpret_cast<uint2*>(
            sT + (wv * 64 + nt * 16 + l15) * LDT + mt * 16 + q * 4) = pk;
      }
    }
    __asm__ __volatile__("s_waitcnt lgkmcnt(0)" ::: "memory");
    #pragma unroll
    for (int rt = 0; rt < 4; ++rt)
      #pragma unroll
      for (int k2 = 0; k2 < 2; ++k2)
        aF[cc][rt][k2] = *reinterpret_cast<const bf16x8*>(
            sT + (wv * 64 + rt * 16 + l15) * LDT + k2 * 32 + q * 8);
    __asm__ __volatile__("s_waitcnt lgkmcnt(0)" ::: "memory");  // WAR guard
  }

  // ---- phase-2/3 scalars: loaded BEFORE any DMA is issued (vmcnt FIFO) ----
  float pb2v[8][2], pw3v[8][2];
  #pragma unroll
  for (int ch = 0; ch < 8; ++ch)
    #pragma unroll
    for (int ct = 0; ct < 2; ++ct) {
      const int n = ch * 32 + ct * 16 + l15;
      pb2v[ch][ct] = b2[c * HD + n];
      pw3v[ch][ct] = W3[c * HD + n];
    }
  const float bb3 = b3[c];

  __syncthreads();   // barrier #1: ALL waves done with sBuf-as-sT (union safety)

  // ---- DMA prologue: W2 chunks 0,1 into sBuf-as-sU (now free) ----
  #pragma unroll
  for (int pc = 0; pc < 2; ++pc) {
    unsigned short* buf = sU + pc * (32 * 256);
    #pragma unroll
    for (int i = 0; i < 4; ++i) {
      const int b2i = wv * 4 + i;            // 1KB unit (2 rows)
      const int r   = b2i * 2 + (lane >> 5); // local row 0..31
      const int j   = (lane & 31) ^ (r & 7); // logical granule
      gl2lds16(W2c + (pc * 32 + r) * 256 + j * 8, buf + b2i * 512);
    }
  }
  __syncthreads();   // barrier #2: drains vmcnt(0) -> chunks 0,1 landed

  // ---- phase 2+3: d = relu(h1 @ W2 + b2) . W3, chunk ping-pong ----
  float dacc[4][4];
  #pragma unroll
  for (int rt = 0; rt < 4; ++rt)
    #pragma unroll
    for (int r = 0; r < 4; ++r) dacc[rt][r] = 0.f;

  #pragma unroll
  for (int ch = 0; ch < 8; ++ch) {
    const unsigned short* buf = sU + (ch & 1) * (32 * 256);

    // b2 folded into MFMA C-in (verified R6): D col = n-col = l15
    f32x4 acc[4][2];
    #pragma unroll
    for (int rt = 0; rt < 4; ++rt)
      #pragma unroll
      for (int ct = 0; ct < 2; ++ct) {
        const float bv = pb2v[ch][ct];
        acc[rt][ct] = (f32x4){bv, bv, bv, bv};
      }

    #pragma unroll
    for (int ks = 0; ks < 8; ++ks) {
      const int jj = ks * 4 + q;            // logical granule of this k-slice
      const int cc = ks >> 1, k2 = ks & 1;
      #pragma unroll
      for (int ct = 0; ct < 2; ++ct) {
        const int nl = ct * 16 + l15;       // local row (= h2 col within chunk)
        bf16x8 b = *reinterpret_cast<const bf16x8*>(
            buf + nl * 256 + ((jj ^ (l15 & 7)) << 3));
        __builtin_amdgcn_s_setprio(1);
        #pragma unroll
        for (int rt = 0; rt < 4; ++rt)
          acc[rt][ct] = __builtin_amdgcn_mfma_f32_16x16x32_bf16(
              aF[cc][rt][k2], b, acc[rt][ct], 0, 0, 0);
        __builtin_amdgcn_s_setprio(0);
      }
    }

    // fused epilogue: relu(h2) dot W3 per row (bias already in C-in)
    #pragma unroll
    for (int ct = 0; ct < 2; ++ct) {
      const float w3v = pw3v[ch][ct];
      #pragma unroll
      for (int rt = 0; rt < 4; ++rt)
        #pragma unroll
        for (int r = 0; r < 4; ++r) {
          float v = acc[rt][ct][r];
          v = v > 0.f ? v : 0.f;
          dacc[rt][r] += v * w3v;
        }
    }

    __syncthreads();   // readers of buf[ch&1] done; drains chunk ch+1's DMA
    if (ch < 6) {      // refill freed buffer with chunk ch+2 (1 chunk in flight)
      unsigned short* nbuf = sU + (ch & 1) * (32 * 256);
      #pragma unroll
      for (int i = 0; i < 4; ++i) {
        const int b2i = wv * 4 + i;
        const int r   = b2i * 2 + (lane >> 5);
        const int j   = (lane & 31) ^ (r & 7);
        gl2lds16(W2c + ((ch + 2) * 32 + r) * 256 + j * 8, nbuf + b2i * 512);
      }
    }
  }

  // ---- reduce over the 16 col-lanes, write out ----
  #pragma unroll
  for (int rt = 0; rt < 4; ++rt)
    #pragma unroll
    for (int r = 0; r < 4; ++r) {
      float v = dacc[rt][r];
      v += __shfl_xor(v, 1);
      v += __shfl_xor(v, 2);
      v += __shfl_xor(v, 4);
      v += __shfl_xor(v, 8);
      dacc[rt][r] = v;
    }

  if (l15 == 0) {
    const int rbase = row0 + wv * 64 + q * 4;
    #pragma unroll
    for (int rt = 0; rt < 4; ++rt)
      #pragma unroll
      for (int r = 0; r < 4; ++r)
        out[(rbase + rt * 16 + r) * C + c] = dacc[rt][r] + bb3;
  }
}

extern "C" void kernel_launch(void* const* d_in, const int* in_sizes, int n_in,
                              void* d_out, int out_size, void* d_ws, size_t ws_size,
                              hipStream_t stream)
{
  const float* st = (const float*)d_in[0];
  const float* W1 = (const float*)d_in[1];
  const float* b1 = (const float*)d_in[2];
  const float* W2 = (const float*)d_in[3];
  const float* b2 = (const float*)d_in[4];
  const float* W3 = (const float*)d_in[5];
  const float* b3 = (const float*)d_in[6];
  float* out = (float*)d_out;

  unsigned short* W1T = (unsigned short*)d_ws;         // 131072 bf16
  unsigned short* W2T = W1T + C * HD * S;              // 524288 bf16

  prep_weights<<<dim3(640), dim3(256), 0, stream>>>(W1, W2, W1T, W2T);
  moe_fused<<<dim3(2048), dim3(256), 0, stream>>>(st, W1T, W2T, b1, b2, W3, b3, out);
}

// Round 12
// 165.531 us; speedup vs baseline: 2.8572x; 2.8572x over previous
//
#include <hip/hip_runtime.h>
#include <hip/hip_bf16.h>

typedef __bf16 bf16x8 __attribute__((ext_vector_type(8)));
typedef float  f32x4  __attribute__((ext_vector_type(4)));

static constexpr int S  = 64;    // DIM_S
static constexpr int C  = 8;     // DIM_C (experts)
static constexpr int HD = 256;   // hidden width

__device__ __forceinline__ unsigned short f2bf(float f) {
  __hip_bfloat16 b = __float2bfloat16(f);
  unsigned short u;
  __builtin_memcpy(&u, &b, 2);
  return u;
}

// async global->LDS DMA, 16 B per lane; lds dest = wave-uniform base + lane*16
__device__ __forceinline__ void gl2lds16(const void* g, void* l) {
  __builtin_amdgcn_global_load_lds(
      (const __attribute__((address_space(1))) unsigned int*)g,
      (__attribute__((address_space(3))) unsigned int*)l, 16, 0, 0);
}

// LDS-tiled transposes, coalesced both sides.  (unchanged, verified)
// blocks 0..511:  W2 [C][256k][256n] -> W2T bf16 [C][256n][256k]
// blocks 512..639: W1 [C][64s][256h] -> W1T bf16 [C][256h][64s]
__global__ __launch_bounds__(256) void prep_weights(
    const float* __restrict__ W1, const float* __restrict__ W2,
    unsigned short* __restrict__ W1T, unsigned short* __restrict__ W2T)
{
  __shared__ float tile[32][33];
  const int tid = threadIdx.x, cl = tid & 31, r0 = tid >> 5;
  const int b = blockIdx.x;
  if (b < 512) {
    const int c = b >> 6, t = b & 63, kt = t >> 3, nt = t & 7;
    const float* src = W2 + c * 65536;
    #pragma unroll
    for (int i = 0; i < 4; ++i) {
      int r = r0 + 8 * i;
      tile[r][cl] = src[(kt * 32 + r) * 256 + nt * 32 + cl];
    }
    __syncthreads();
    unsigned short* dst = W2T + c * 65536;
    #pragma unroll
    for (int i = 0; i < 4; ++i) {
      int r = r0 + 8 * i;
      dst[(nt * 32 + r) * 256 + kt * 32 + cl] = f2bf(tile[cl][r]);
    }
  } else {
    const int bb = b - 512;
    const int c = bb >> 4, t = bb & 15, st2 = t >> 3, ht = t & 7;
    const float* src = W1 + c * 16384;
    #pragma unroll
    for (int i = 0; i < 4; ++i) {
      int r = r0 + 8 * i;
      tile[r][cl] = src[(st2 * 32 + r) * 256 + ht * 32 + cl];
    }
    __syncthreads();
    unsigned short* dst = W1T + c * 16384;
    #pragma unroll
    for (int i = 0; i < 4; ++i) {
      int r = r0 + 8 * i;
      dst[(ht * 32 + r) * 64 + st2 * 32 + cl] = f2bf(tile[cl][r]);
    }
  }
}

// One block: 256 batch rows x 1 expert. 4 waves, 64 rows/wave. 16x16x32 MFMA.
// = R6/R10 lineage (best verified) with two stall-removal changes, no
// register-structure change (R11 post-mortem: occupancy is reg-capped at
// 2 waves/SIMD; ~200 unified regs/wave is the design invariant):
//  (1) sT is GONE: phase-1 D -> phase-2 A-frag transpose done fully
//      in-register via v_permlane32_swap_b32 + v_permlane16_swap_b32
//      (exact replacement of the verified sT mapping: for hidden
//      h = k2*32+q*8+e, src mt-parity = q>>1, src quad = 2(q&1)+(e>>2),
//      src reg = e&3).  Phase 1 is now 100% LDS-free; 8 lgkmcnt(0)
//      round-trips per wave deleted.
//  (2) sU = 64KB (4 W2 chunks resident, two 2-chunk halves).  Chunks 0-3
//      DMA at kernel start (hidden under phase 1); phase 2 processes 2
//      chunks per barrier with half ping-pong.  Barriers 9 -> 5.
__global__ __launch_bounds__(256, 2) void moe_fused(
    const float* __restrict__ st,
    const unsigned short* __restrict__ W1T,
    const unsigned short* __restrict__ W2T,
    const float* __restrict__ b1,
    const float* __restrict__ b2,
    const float* __restrict__ W3,
    const float* __restrict__ b3,
    float* __restrict__ out)
{
  __shared__ __align__(16) unsigned short sU[4 * 32 * 256];   // 65536 B, 4 chunks

  const int tid  = threadIdx.x;
  const int lane = tid & 63;
  const int wv   = tid >> 6;          // wave -> batch rows [wv*64, wv*64+64)
  const int l15  = lane & 15;
  const int q    = lane >> 4;
  const int c    = blockIdx.x >> 8;
  const int row0 = (blockIdx.x & 255) * 256;
  const int wrow = row0 + wv * 64;

  const unsigned short* W1c = W1T + c * HD * S;
  const unsigned short* W2c = W2T + c * HD * HD;

  // ---- raw st loads FIRST (oldest in vmcnt FIFO) ----
  float4 sraw[8][2];   // transient
  #pragma unroll
  for (int nt = 0; nt < 4; ++nt)
    #pragma unroll
    for (int ks = 0; ks < 2; ++ks) {
      const float* rp = st + (size_t)(wrow + nt * 16 + l15) * S + ks * 32 + q * 8;
      sraw[ks * 4 + nt][0] = *reinterpret_cast<const float4*>(rp);
      sraw[ks * 4 + nt][1] = *reinterpret_cast<const float4*>(rp + 4);
    }

  // ---- DMA prologue: W2 chunks 0..3 into sU (latency hides under phase 1,
  // drained by barrier #1) ----
  #pragma unroll
  for (int ck = 0; ck < 4; ++ck) {
    unsigned short* buf = sU + ck * 8192;
    #pragma unroll
    for (int i = 0; i < 4; ++i) {
      const int b2i = wv * 4 + i;            // 1KB unit (2 rows)
      const int r   = b2i * 2 + (lane >> 5); // local row 0..31
      const int j   = (lane & 31) ^ (r & 7); // logical granule
      gl2lds16(W2c + (ck * 32 + r) * 256 + j * 8, buf + b2i * 512);
    }
  }

  // ---- convert st -> phase-1 B-frags (cvt_pk), kept in registers ----
  bf16x8 bB[2][4];   // [ks][nt]
  #pragma unroll
  for (int nt = 0; nt < 4; ++nt)
    #pragma unroll
    for (int ks = 0; ks < 2; ++ks) {
      float4 x = sraw[ks * 4 + nt][0], y = sraw[ks * 4 + nt][1];
      union { bf16x8 v; unsigned u[4]; } pk;
      __asm__("v_cvt_pk_bf16_f32 %0, %1, %2" : "=v"(pk.u[0]) : "v"(x.x), "v"(x.y));
      __asm__("v_cvt_pk_bf16_f32 %0, %1, %2" : "=v"(pk.u[1]) : "v"(x.z), "v"(x.w));
      __asm__("v_cvt_pk_bf16_f32 %0, %1, %2" : "=v"(pk.u[2]) : "v"(y.x), "v"(y.y));
      __asm__("v_cvt_pk_bf16_f32 %0, %1, %2" : "=v"(pk.u[3]) : "v"(y.z), "v"(y.w));
      bB[ks][nt] = pk.v;
    }

  // ---- phase 1: h1^T = W1^T @ st^T, 4 quarters of 64 hidden; LDS-free ----
  bf16x8 aF[4][4][2];  // [cc][rt][k2]: phase-2 A-frags (m=batch l15, k=hidden)
  #pragma unroll
  for (int cc = 0; cc < 4; ++cc) {
    f32x4 bias[4];
    #pragma unroll
    for (int mt = 0; mt < 4; ++mt)
      bias[mt] = *reinterpret_cast<const f32x4*>(
          b1 + c * HD + cc * 64 + mt * 16 + q * 4);

    // b1 folded into MFMA C-in (verified): D row = hidden = q*4+j
    f32x4 acc[4][4];   // [mt(hidden)][nt(batch)]
    #pragma unroll
    for (int mt = 0; mt < 4; ++mt)
      #pragma unroll
      for (int nt = 0; nt < 4; ++nt)
        acc[mt][nt] = bias[mt];

    #pragma unroll
    for (int ks = 0; ks < 2; ++ks) {
      bf16x8 aW[4];
      #pragma unroll
      for (int mt = 0; mt < 4; ++mt)
        aW[mt] = *reinterpret_cast<const bf16x8*>(
            W1c + (cc * 64 + mt * 16 + l15) * S + ks * 32 + q * 8);
      __builtin_amdgcn_s_setprio(1);
      #pragma unroll
      for (int mt = 0; mt < 4; ++mt)
        #pragma unroll
        for (int nt = 0; nt < 4; ++nt)
          acc[mt][nt] = __builtin_amdgcn_mfma_f32_16x16x32_bf16(
              aW[mt], bB[ks][nt], acc[mt][nt], 0, 0, 0);
      __builtin_amdgcn_s_setprio(0);
    }

    // epilogue: relu -> cvt_pk -> in-register transpose to A-frag layout.
    // E regs = mt 2k2 (even), O regs = mt 2k2+1 (odd):
    //   swap32(E,O); swap16(E,O) => E-chain = words {e01,e23}? no:
    //   (E0,O0) -> w0 (e01) in E0, w2 (e45) in O0; (E1,O1) -> w1,w3.
    #pragma unroll
    for (int nt = 0; nt < 4; ++nt) {
      #pragma unroll
      for (int k2 = 0; k2 < 2; ++k2) {
        const f32x4& E = acc[2 * k2][nt];
        const f32x4& O = acc[2 * k2 + 1][nt];
        float e0 = E[0] > 0.f ? E[0] : 0.f, e1 = E[1] > 0.f ? E[1] : 0.f;
        float e2 = E[2] > 0.f ? E[2] : 0.f, e3 = E[3] > 0.f ? E[3] : 0.f;
        float o0 = O[0] > 0.f ? O[0] : 0.f, o1 = O[1] > 0.f ? O[1] : 0.f;
        float o2 = O[2] > 0.f ? O[2] : 0.f, o3 = O[3] > 0.f ? O[3] : 0.f;
        unsigned dE0, dE1, dO0, dO1;
        __asm__("v_cvt_pk_bf16_f32 %0, %1, %2" : "=v"(dE0) : "v"(e0), "v"(e1));
        __asm__("v_cvt_pk_bf16_f32 %0, %1, %2" : "=v"(dE1) : "v"(e2), "v"(e3));
        __asm__("v_cvt_pk_bf16_f32 %0, %1, %2" : "=v"(dO0) : "v"(o0), "v"(o1));
        __asm__("v_cvt_pk_bf16_f32 %0, %1, %2" : "=v"(dO1) : "v"(o2), "v"(o3));
        __asm__("v_permlane32_swap_b32 %0, %1" : "+v"(dE0), "+v"(dO0));
        __asm__("v_permlane16_swap_b32 %0, %1" : "+v"(dE0), "+v"(dO0));
        __asm__("v_permlane32_swap_b32 %0, %1" : "+v"(dE1), "+v"(dO1));
        __asm__("v_permlane16_swap_b32 %0, %1" : "+v"(dE1), "+v"(dO1));
        union { unsigned u[4]; bf16x8 v; } f;
        f.u[0] = dE0;   // e0,e1
        f.u[1] = dE1;   // e2,e3
        f.u[2] = dO0;   // e4,e5
        f.u[3] = dO1;   // e6,e7
        aF[cc][nt][k2] = f.v;
      }
    }
  }

  // ---- phase-2/3 scalars ----
  float pb2v[8][2], pw3v[8][2];
  #pragma unroll
  for (int ch = 0; ch < 8; ++ch)
    #pragma unroll
    for (int ct = 0; ct < 2; ++ct) {
      const int n = ch * 32 + ct * 16 + l15;
      pb2v[ch][ct] = b2[c * HD + n];
      pw3v[ch][ct] = W3[c * HD + n];
    }
  const float bb3 = b3[c];

  __syncthreads();   // barrier #1: drains vmcnt -> chunks 0..3 landed

  // ---- phase 2+3: d = relu(h1 @ W2 + b2) . W3, 2 chunks per barrier ----
  float dacc[4][4];
  #pragma unroll
  for (int rt = 0; rt < 4; ++rt)
    #pragma unroll
    for (int r = 0; r < 4; ++r) dacc[rt][r] = 0.f;

  #pragma unroll
  for (int pg = 0; pg < 4; ++pg) {
    const int bsel = pg & 1;
    #pragma unroll
    for (int sub = 0; sub < 2; ++sub) {
      const int ch = 2 * pg + sub;
      const unsigned short* buf = sU + bsel * 16384 + sub * 8192;

      // b2 folded into MFMA C-in (verified): D col = n-col = l15
      f32x4 acc[4][2];
      #pragma unroll
      for (int rt = 0; rt < 4; ++rt)
        #pragma unroll
        for (int ct = 0; ct < 2; ++ct) {
          const float bv = pb2v[ch][ct];
          acc[rt][ct] = (f32x4){bv, bv, bv, bv};
        }

      #pragma unroll
      for (int ks = 0; ks < 8; ++ks) {
        const int jj = ks * 4 + q;            // logical granule of this k-slice
        const int cc = ks >> 1, k2 = ks & 1;
        #pragma unroll
        for (int ct = 0; ct < 2; ++ct) {
          const int nl = ct * 16 + l15;       // local row (= h2 col in chunk)
          bf16x8 b = *reinterpret_cast<const bf16x8*>(
              buf + nl * 256 + ((jj ^ (l15 & 7)) << 3));
          __builtin_amdgcn_s_setprio(1);
          #pragma unroll
          for (int rt = 0; rt < 4; ++rt)
            acc[rt][ct] = __builtin_amdgcn_mfma_f32_16x16x32_bf16(
                aF[cc][rt][k2], b, acc[rt][ct], 0, 0, 0);
          __builtin_amdgcn_s_setprio(0);
        }
      }

      // fused epilogue: relu(h2) dot W3 per row (bias already in C-in)
      #pragma unroll
      for (int ct = 0; ct < 2; ++ct) {
        const float w3v = pw3v[ch][ct];
        #pragma unroll
        for (int rt = 0; rt < 4; ++rt)
          #pragma unroll
          for (int r = 0; r < 4; ++r) {
            float v = acc[rt][ct][r];
            v = v > 0.f ? v : 0.f;
            dacc[rt][r] += v * w3v;
          }
      }
    }

    __syncthreads();   // readers of half bsel done; drains prior refill DMA
    if (pg < 2) {      // refill half bsel with chunks 2pg+4, 2pg+5
      #pragma unroll
      for (int sub = 0; sub < 2; ++sub) {
        unsigned short* nbuf = sU + bsel * 16384 + sub * 8192;
        const int ch = 2 * pg + 4 + sub;
        #pragma unroll
        for (int i = 0; i < 4; ++i) {
          const int b2i = wv * 4 + i;
          const int r   = b2i * 2 + (lane >> 5);
          const int j   = (lane & 31) ^ (r & 7);
          gl2lds16(W2c + (ch * 32 + r) * 256 + j * 8, nbuf + b2i * 512);
        }
      }
    }
  }

  // ---- reduce over the 16 col-lanes, write out ----
  #pragma unroll
  for (int rt = 0; rt < 4; ++rt)
    #pragma unroll
    for (int r = 0; r < 4; ++r) {
      float v = dacc[rt][r];
      v += __shfl_xor(v, 1);
      v += __shfl_xor(v, 2);
      v += __shfl_xor(v, 4);
      v += __shfl_xor(v, 8);
      dacc[rt][r] = v;
    }

  if (l15 == 0) {
    const int rbase = row0 + wv * 64 + q * 4;
    #pragma unroll
    for (int rt = 0; rt < 4; ++rt)
      #pragma unroll
      for (int r = 0; r < 4; ++r)
        out[(rbase + rt * 16 + r) * C + c] = dacc[rt][r] + bb3;
  }
}

extern "C" void kernel_launch(void* const* d_in, const int* in_sizes, int n_in,
                              void* d_out, int out_size, void* d_ws, size_t ws_size,
                              hipStream_t stream)
{
  const float* st = (const float*)d_in[0];
  const float* W1 = (const float*)d_in[1];
  const float* b1 = (const float*)d_in[2];
  const float* W2 = (const float*)d_in[3];
  const float* b2 = (const float*)d_in[4];
  const float* W3 = (const float*)d_in[5];
  const float* b3 = (const float*)d_in[6];
  float* out = (float*)d_out;

  unsigned short* W1T = (unsigned short*)d_ws;         // 131072 bf16
  unsigned short* W2T = W1T + C * HD * S;              // 524288 bf16

  prep_weights<<<dim3(640), dim3(256), 0, stream>>>(W1, W2, W1T, W2T);
  moe_fused<<<dim3(2048), dim3(256), 0, stream>>>(st, W1T, W2T, b1, b2, W3, b3, out);
}